// Round 14
// baseline (124.642 us; speedup 1.0000x reference)
//
#include <hip/hip_runtime.h>

#define N_NODES 4096
#define DMODEL  256
#define NHEAD   8
#define HDIM    32
#define LN_EPS  1e-5f
#define MAXDEG  64   // padded-CSR row capacity (Poisson λ≈17, P(>64)≈0)

typedef __attribute__((ext_vector_type(8))) short short8;
typedef __attribute__((ext_vector_type(4))) float f32x4;

__device__ __forceinline__ unsigned short f2bf(float f) {
  unsigned int x = __float_as_uint(f);
  x += 0x7fffu + ((x >> 16) & 1u);   // round-to-nearest-even
  return (unsigned short)(x >> 16);
}
__device__ __forceinline__ float bf2f(unsigned short u) {
  return __uint_as_float(((unsigned int)u) << 16);
}

// Grid barrier: all blocks resident by construction (256 blocks <= 256 CUs).
// Release fence (agent scope, L2 writeback) -> arrive -> poll -> acquire fence.
__device__ __forceinline__ void gbar(unsigned int* ctr, unsigned int target) {
  __syncthreads();
  if (threadIdx.x == 0) {
    __threadfence();   // release: flush this XCD's L2 so others see our stores
    __hip_atomic_fetch_add(ctr, 1u, __ATOMIC_SEQ_CST, __HIP_MEMORY_SCOPE_AGENT);
    while (__hip_atomic_load(ctr, __ATOMIC_SEQ_CST, __HIP_MEMORY_SCOPE_AGENT) < target)
      __builtin_amdgcn_s_sleep(8);
    __threadfence();   // acquire: invalidate caches before reading others' data
  }
  __syncthreads();
}

// Single fused kernel, 256 blocks x 1024 thr:
//  P0: weight transpose/cvt (1 tile/block) + bits/cnt clears (spare threads)
//  P1: QKV GEMM (16 waves x 16 cols x 3 mats) + edge dedup+scatter
//  P2: sparse attention (8 lanes/(node,head)) + out-GEMM + residual + LN
__global__ __launch_bounds__(1024, 1) void fused_all(
    const float* __restrict__ x, const int* __restrict__ edges, int ne,
    const float* __restrict__ Wq, const float* __restrict__ bq,
    const float* __restrict__ Wk, const float* __restrict__ bk,
    const float* __restrict__ Wv, const float* __restrict__ bv,
    const float* __restrict__ Wo, const float* __restrict__ bo,
    const float* __restrict__ gamma, const float* __restrict__ beta,
    unsigned short* wt, unsigned short* Qb, unsigned short* Kb,
    unsigned short* Vb, unsigned int* bits, int* cnt, int* colidx,
    unsigned int* ctr, float* __restrict__ out) {
  __shared__ float t[32][33];
  __shared__ unsigned short att_lds[16][264];
  __shared__ float ylds[16][260];
  __shared__ float ps[16][65], pq[16][65];
  __shared__ float mu_s[16], ri_s[16];

  const int tid = threadIdx.x;
  const int bid = blockIdx.x;
  const int* e0 = edges;
  const int* e1 = edges + ne;
  const float scale = 0.17677669529663687f;  // 1/sqrt(32)

  // ---------------- P0: weight staging + clears ----------------
  {
    int kbi = bid & 7, nbi = (bid >> 3) & 7, m = bid >> 6;
    const float* w = (m == 0) ? Wq : (m == 1) ? Wk : (m == 2) ? Wv : Wo;
    int kb = kbi * 32, nb = nbi * 32;
    if (tid < 256) {
      int tx = tid & 31, ty = tid >> 5;
#pragma unroll
      for (int r = 0; r < 32; r += 8)
        t[ty + r][tx] = w[(kb + ty + r) * 256 + nb + tx];   // coalesced in n
    } else {
      int j = bid * 768 + (tid - 256);
      if (j < ne) {
        unsigned int bitpos = ((unsigned int)e0[j] << 12) | (unsigned int)e1[j];
        bits[bitpos >> 5] = 0u;
      }
      if (j < N_NODES) cnt[j] = 0;
    }
    __syncthreads();
    if (tid < 256) {
      int tx = tid & 31, ty = tid >> 5;
      unsigned short* o = wt + m * 65536;
      // Wt layout: [m][kk][kgrp][n][8j]; thread (tx, ty+r) holds (n=nb+ty+r, k=kb+tx)
#pragma unroll
      for (int r = 0; r < 32; r += 8)
        o[(kbi * 4 + (tx >> 3)) * 2048 + (nb + ty + r) * 8 + (tx & 7)] =
            f2bf(t[tx][ty + r]);
    }
  }
  gbar(ctr, 256);

  // ---------------- P1: QKV GEMM + edge scatter ----------------
  {
    int lane = tid & 63, w = tid >> 6;   // 16 waves
    int Mbase = bid * 16;
    int arow = lane & 15, kgrp = lane >> 4;
    short8 a[8];
    const float* ab = x + (Mbase + arow) * 256 + kgrp * 8;
#pragma unroll
    for (int kk = 0; kk < 8; ++kk) {
      float4 v0 = *reinterpret_cast<const float4*>(ab + kk * 32);
      float4 v1 = *reinterpret_cast<const float4*>(ab + kk * 32 + 4);
      short8 tv;
      tv[0] = (short)f2bf(v0.x); tv[1] = (short)f2bf(v0.y);
      tv[2] = (short)f2bf(v0.z); tv[3] = (short)f2bf(v0.w);
      tv[4] = (short)f2bf(v1.x); tv[5] = (short)f2bf(v1.y);
      tv[6] = (short)f2bf(v1.z); tv[7] = (short)f2bf(v1.w);
      a[kk] = tv;
    }
#pragma unroll
    for (int mat = 0; mat < 3; ++mat) {
      const unsigned short* wm = wt + mat * 65536;
      const float* bias_p = (mat == 0) ? bq : (mat == 1) ? bk : bv;
      unsigned short* o = (mat == 0) ? Qb : (mat == 1) ? Kb : Vb;
      int col = w * 16 + arow;
      const unsigned short* bb = wm + kgrp * 2048 + col * 8;
      f32x4 acc = {0.f, 0.f, 0.f, 0.f};
#pragma unroll
      for (int kk = 0; kk < 8; ++kk) {
        short8 b = *reinterpret_cast<const short8*>(bb + kk * 8192);
        acc = __builtin_amdgcn_mfma_f32_16x16x32_bf16(a[kk], b, acc, 0, 0, 0);
      }
      float bias = bias_p[col];
#pragma unroll
      for (int r = 0; r < 4; ++r) {
        int row = Mbase + kgrp * 4 + r;
        o[row * 256 + col] = f2bf(acc[r] + bias);
      }
    }
    // edge dedup + scatter (this block's slice)
    int epb = (ne + 255) >> 8;
    for (int tt = tid; tt < epb; tt += 1024) {
      int i = bid * epb + tt;
      if (i < ne) {
        int s = e0[i], d = e1[i];
        unsigned int bitpos = ((unsigned int)s << 12) | (unsigned int)d;
        unsigned int word = bitpos >> 5, msk = 1u << (bitpos & 31);
        unsigned int old = atomicOr(&bits[word], msk);
        if (!(old & msk)) {
          int pos = atomicAdd(&cnt[s], 1);
          if (pos < MAXDEG) colidx[s * MAXDEG + pos] = d;
        }
      }
    }
  }
  gbar(ctr, 512);

  // ---------------- P2: attention + out-GEMM + residual + LN ----------------
  {
    int Mbase = bid * 16;
    // attention: 8 lanes per (node, head)
    {
      int g = tid >> 3;            // 128 groups = 16 nodes x 8 heads
      int gl = tid & 7;
      int ni = g >> 3, h = g & 7;
      int n = Mbase + ni;

      float qf[32];
      {
        const short8* q8 = reinterpret_cast<const short8*>(Qb + n * 256 + h * 32);
#pragma unroll
        for (int b = 0; b < 4; ++b) {
          short8 qv = q8[b];
#pragma unroll
          for (int j = 0; j < 8; ++j)
            qf[b * 8 + j] = bf2f((unsigned short)qv[j]) * scale;
        }
      }

      int deg = cnt[n]; deg = (deg > MAXDEG) ? MAXDEG : deg;
      const int* nbrs = colidx + n * MAXDEG;

      float s[8]; int c[8];
#pragma unroll
      for (int i = 0; i < 8; ++i) { s[i] = -3.0e38f; c[i] = 0; }
#pragma unroll
      for (int i = 0; i < 8; ++i) {
        if (8 * i >= deg) break;
        int idx = 8 * i + gl;
        if (idx < deg) {
          c[i] = nbrs[idx];
          const short8* k8 = reinterpret_cast<const short8*>(Kb + c[i] * 256 + h * 32);
          float d = 0.f;
#pragma unroll
          for (int b = 0; b < 4; ++b) {
            short8 kv = k8[b];
#pragma unroll
            for (int j = 0; j < 8; ++j)
              d += qf[b * 8 + j] * bf2f((unsigned short)kv[j]);
          }
          s[i] = d;
        }
      }

      float gm = s[0];
#pragma unroll
      for (int i = 1; i < 8; ++i) gm = fmaxf(gm, s[i]);
      gm = fmaxf(gm, __shfl_xor(gm, 1, 8));
      gm = fmaxf(gm, __shfl_xor(gm, 2, 8));
      gm = fmaxf(gm, __shfl_xor(gm, 4, 8));

      float l = 0.f;
#pragma unroll
      for (int i = 0; i < 8; ++i) {
        if (8 * i >= deg) break;
        s[i] = __expf(s[i] - gm);
        l += s[i];
      }
      l += __shfl_xor(l, 1, 8);
      l += __shfl_xor(l, 2, 8);
      l += __shfl_xor(l, 4, 8);

      float a0 = 0.f, a1 = 0.f, a2 = 0.f, a3 = 0.f;
#pragma unroll
      for (int i = 0; i < 8; ++i) {
        if (8 * i >= deg) break;
#pragma unroll
        for (int lj = 0; lj < 8; ++lj) {
          if (8 * i + lj >= deg) break;
          float pj = __shfl(s[i], lj, 8);
          int cj = __shfl(c[i], lj, 8);
          ushort4 vv = *reinterpret_cast<const ushort4*>(Vb + cj * 256 + h * 32 + gl * 4);
          a0 += pj * bf2f(vv.x);
          a1 += pj * bf2f(vv.y);
          a2 += pj * bf2f(vv.z);
          a3 += pj * bf2f(vv.w);
        }
      }
      float rl = 1.f / l;
      ushort4 pkt;
      pkt.x = f2bf(a0 * rl); pkt.y = f2bf(a1 * rl);
      pkt.z = f2bf(a2 * rl); pkt.w = f2bf(a3 * rl);
      *reinterpret_cast<ushort4*>(&att_lds[ni][h * 32 + gl * 4]) = pkt;
    }
    __syncthreads();

    // out-GEMM (16 waves x 16 cols)
    {
      int lane = tid & 63, w = tid >> 6;
      int arow = lane & 15, kgrp = lane >> 4;
      const unsigned short* wot = wt + 3 * 65536;

      short8 a[8];
#pragma unroll
      for (int kk = 0; kk < 8; ++kk)
        a[kk] = *reinterpret_cast<const short8*>(&att_lds[arow][kgrp * 8 + kk * 32]);

      int col = w * 16 + arow;
      const unsigned short* bb = wot + kgrp * 2048 + col * 8;
      f32x4 acc = {0.f, 0.f, 0.f, 0.f};
#pragma unroll
      for (int kk = 0; kk < 8; ++kk) {
        short8 b = *reinterpret_cast<const short8*>(bb + kk * 8192);
        acc = __builtin_amdgcn_mfma_f32_16x16x32_bf16(a[kk], b, acc, 0, 0, 0);
      }
      float bof = bo[col];
#pragma unroll
      for (int r = 0; r < 4; ++r) {
        int row = kgrp * 4 + r;
        float xv = x[(Mbase + row) * 256 + col];
        ylds[row][col] = acc[r] + bof + xv;
      }
    }
    __syncthreads();

    // LayerNorm (16 rows x 64 segs of 4)
    int r = tid >> 6, seg = tid & 63;
    float sm = 0.f, sq = 0.f;
#pragma unroll
    for (int j = 0; j < 4; ++j) {
      float v = ylds[r][seg * 4 + j];
      sm += v;
      sq += v * v;
    }
    ps[r][seg] = sm;
    pq[r][seg] = sq;
    __syncthreads();
    if (tid < 16) {
      float S = 0.f, Q2 = 0.f;
#pragma unroll
      for (int cc = 0; cc < 64; ++cc) { S += ps[tid][cc]; Q2 += pq[tid][cc]; }
      float mu = S * (1.f / 256.f);
      float var = Q2 * (1.f / 256.f) - mu * mu;
      mu_s[tid] = mu;
      ri_s[tid] = rsqrtf(var + LN_EPS);
    }
    __syncthreads();
    float mu = mu_s[r], ri = ri_s[r];
    float* orow = out + (Mbase + r) * 256;
#pragma unroll
    for (int j = 0; j < 4; ++j) {
      int cc = seg * 4 + j;
      float v = (ylds[r][cc] - mu) * ri * gamma[cc] + beta[cc];
      orow[cc] = v;
    }
  }
}

// ---------------------------------------------------------------------------
extern "C" void kernel_launch(void* const* d_in, const int* in_sizes, int n_in,
                              void* d_out, int out_size, void* d_ws, size_t ws_size,
                              hipStream_t stream) {
  const float* x     = (const float*)d_in[0];
  const int*   edges = (const int*)d_in[1];
  const float* Wq    = (const float*)d_in[2];
  const float* bq    = (const float*)d_in[3];
  const float* Wk    = (const float*)d_in[4];
  const float* bk    = (const float*)d_in[5];
  const float* Wv    = (const float*)d_in[6];
  const float* bv    = (const float*)d_in[7];
  const float* Wo    = (const float*)d_in[8];
  const float* bo    = (const float*)d_in[9];
  const float* gamma = (const float*)d_in[10];
  const float* beta  = (const float*)d_in[11];
  float* out = (float*)d_out;
  int NE = in_sizes[1] / 2;

  // workspace carve (256B aligned)
  char* p = (char*)d_ws;
  auto carve = [&](size_t sz) { char* r = p; p += ((sz + 255) / 256) * 256; return r; };
  unsigned short* Wt   = (unsigned short*)carve(4 * 65536 * sizeof(unsigned short));
  unsigned short* Qb   = (unsigned short*)carve((size_t)N_NODES * DMODEL * sizeof(unsigned short));
  unsigned short* Kb   = (unsigned short*)carve((size_t)N_NODES * DMODEL * sizeof(unsigned short));
  unsigned short* Vb   = (unsigned short*)carve((size_t)N_NODES * DMODEL * sizeof(unsigned short));
  unsigned int*   bits = (unsigned int*)carve((size_t)N_NODES * N_NODES / 8);
  int*            cnt  = (int*)carve(N_NODES * sizeof(int));
  int*            colidx = (int*)carve((size_t)N_NODES * MAXDEG * sizeof(int));
  unsigned int*   ctr  = (unsigned int*)carve(256);

  hipMemsetAsync(ctr, 0, sizeof(unsigned int), stream);
  fused_all<<<256, 1024, 0, stream>>>(x, edges, NE, Wq, bq, Wk, bk, Wv, bv,
                                      Wo, bo, gamma, beta, Wt, Qb, Kb, Vb,
                                      bits, cnt, colidx, ctr, out);
}

// Round 15
// 70.462 us; speedup vs baseline: 1.7689x; 1.7689x over previous
//
#include <hip/hip_runtime.h>

#define N_NODES 4096
#define DMODEL  256
#define NHEAD   8
#define HDIM    32
#define LN_EPS  1e-5f
#define MAXDEG  64   // padded-CSR row capacity (Poisson λ≈17, P(>64)≈0)

typedef __attribute__((ext_vector_type(8))) short short8;
typedef __attribute__((ext_vector_type(4))) float f32x4;

__device__ __forceinline__ unsigned short f2bf(float f) {
  unsigned int x = __float_as_uint(f);
  x += 0x7fffu + ((x >> 16) & 1u);   // round-to-nearest-even
  return (unsigned short)(x >> 16);
}
__device__ __forceinline__ float bf2f(unsigned short u) {
  return __uint_as_float(((unsigned int)u) << 16);
}

// Load a B-fragment (col fixed, k = kbase..kbase+7) directly from f32 W[k][n].
__device__ __forceinline__ short8 wfrag(const float* __restrict__ W,
                                        int kbase, int col) {
  const float* wp = W + (size_t)kbase * 256 + col;
  short8 b;
#pragma unroll
  for (int j = 0; j < 8; ++j) b[j] = (short)f2bf(wp[j * 256]);
  return b;
}

// ---- K1: QKV GEMM (direct-f32 weights) + row-partitioned CSR build ---------
// 256 blocks x 1024 thr. Block b: GEMM rows [16b,16b+16) (16 waves x 16 cols
// x 3 mats) + edge scan with LDS-bitmap dedup for its 16 rows.
__global__ __launch_bounds__(1024, 1) void qkv_csr(
    const float* __restrict__ x,
    const float* __restrict__ Wq, const float* __restrict__ bq,
    const float* __restrict__ Wk, const float* __restrict__ bk,
    const float* __restrict__ Wv, const float* __restrict__ bv,
    const int* __restrict__ e0, const int* __restrict__ e1, int ne,
    int* __restrict__ cnt, int* __restrict__ colidx,
    unsigned short* __restrict__ Qb, unsigned short* __restrict__ Kb,
    unsigned short* __restrict__ Vb) {
  __shared__ unsigned int bm[16 * 128];   // 16 rows x 4096-bit dedup bitmap
  __shared__ int lcnt[16];

  const int tid = threadIdx.x;
  const int bid = blockIdx.x;
  const int Mbase = bid * 16;

  // ---- CSR build: init LDS ----
  for (int i = tid; i < 2048; i += 1024) bm[i] = 0u;
  if (tid < 16) lcnt[tid] = 0;
  __syncthreads();

  // ---- GEMM (independent of scan; issue first for ILP) ----
  {
    int lane = tid & 63, w = tid >> 6;   // 16 waves
    int arow = lane & 15, kgrp = lane >> 4;
    short8 a[8];
    const float* ab = x + (Mbase + arow) * 256 + kgrp * 8;
#pragma unroll
    for (int kk = 0; kk < 8; ++kk) {
      float4 v0 = *reinterpret_cast<const float4*>(ab + kk * 32);
      float4 v1 = *reinterpret_cast<const float4*>(ab + kk * 32 + 4);
      short8 tv;
      tv[0] = (short)f2bf(v0.x); tv[1] = (short)f2bf(v0.y);
      tv[2] = (short)f2bf(v0.z); tv[3] = (short)f2bf(v0.w);
      tv[4] = (short)f2bf(v1.x); tv[5] = (short)f2bf(v1.y);
      tv[6] = (short)f2bf(v1.z); tv[7] = (short)f2bf(v1.w);
      a[kk] = tv;
    }
    int col = w * 16 + arow;
#pragma unroll
    for (int mat = 0; mat < 3; ++mat) {
      const float* W = (mat == 0) ? Wq : (mat == 1) ? Wk : Wv;
      const float* bias_p = (mat == 0) ? bq : (mat == 1) ? bk : bv;
      unsigned short* o = (mat == 0) ? Qb : (mat == 1) ? Kb : Vb;
      f32x4 acc = {0.f, 0.f, 0.f, 0.f};
#pragma unroll
      for (int kk = 0; kk < 8; ++kk) {
        short8 b = wfrag(W, kk * 32 + kgrp * 8, col);
        acc = __builtin_amdgcn_mfma_f32_16x16x32_bf16(a[kk], b, acc, 0, 0, 0);
      }
      float bias = bias_p[col];
#pragma unroll
      for (int r = 0; r < 4; ++r) {
        int row = Mbase + kgrp * 4 + r;
        o[row * 256 + col] = f2bf(acc[r] + bias);
      }
    }
  }

  // ---- CSR build: scan all edges, keep those landing in our 16 rows ----
  for (int i = tid; i < ne; i += 1024) {
    int s = e0[i];
    if ((s >> 4) == bid) {
      int d = e1[i];
      int li = s & 15;
      unsigned int msk = 1u << (d & 31);
      unsigned int old = atomicOr(&bm[li * 128 + (d >> 5)], msk);
      if (!(old & msk)) {
        int pos = atomicAdd(&lcnt[li], 1);
        if (pos < MAXDEG) colidx[s * MAXDEG + pos] = d;
      }
    }
  }
  __syncthreads();
  if (tid < 16) cnt[Mbase + tid] = lcnt[tid];
}

// ---- K2: attention + out-GEMM (direct-f32 Wo) + residual + LayerNorm ------
__global__ __launch_bounds__(1024, 1) void attn_out_ln(
    const unsigned short* __restrict__ Qb, const unsigned short* __restrict__ Kb,
    const unsigned short* __restrict__ Vb, const int* __restrict__ cnt,
    const int* __restrict__ colidx, const float* __restrict__ Wo,
    const float* __restrict__ bo, const float* __restrict__ x,
    const float* __restrict__ gamma, const float* __restrict__ beta,
    float* __restrict__ out) {
  __shared__ unsigned short att_lds[16][264];  // bf16, 528B row
  __shared__ float ylds[16][260];
  __shared__ float ps[16][65], pq[16][65];
  __shared__ float mu_s[16], ri_s[16];

  int tid = threadIdx.x;
  int Mbase = blockIdx.x * 16;
  const float scale = 0.17677669529663687f;  // 1/sqrt(32)

  // ---------- attention: 8 lanes per (node, head) ----------
  {
    int g = tid >> 3;            // 128 groups = 16 nodes x 8 heads
    int gl = tid & 7;
    int ni = g >> 3, h = g & 7;
    int n = Mbase + ni;

    float qf[32];
    {
      const short8* q8 = reinterpret_cast<const short8*>(Qb + n * 256 + h * 32);
#pragma unroll
      for (int b = 0; b < 4; ++b) {
        short8 qv = q8[b];
#pragma unroll
        for (int j = 0; j < 8; ++j)
          qf[b * 8 + j] = bf2f((unsigned short)qv[j]) * scale;
      }
    }

    int deg = cnt[n]; deg = (deg > MAXDEG) ? MAXDEG : deg;
    const int* nbrs = colidx + n * MAXDEG;

    float s[8]; int c[8];
#pragma unroll
    for (int i = 0; i < 8; ++i) { s[i] = -3.0e38f; c[i] = 0; }
#pragma unroll
    for (int i = 0; i < 8; ++i) {
      if (8 * i >= deg) break;
      int idx = 8 * i + gl;
      if (idx < deg) {
        c[i] = nbrs[idx];
        const short8* k8 = reinterpret_cast<const short8*>(Kb + c[i] * 256 + h * 32);
        float d = 0.f;
#pragma unroll
        for (int b = 0; b < 4; ++b) {
          short8 kv = k8[b];
#pragma unroll
          for (int j = 0; j < 8; ++j)
            d += qf[b * 8 + j] * bf2f((unsigned short)kv[j]);
        }
        s[i] = d;
      }
    }

    float gm = s[0];
#pragma unroll
    for (int i = 1; i < 8; ++i) gm = fmaxf(gm, s[i]);
    gm = fmaxf(gm, __shfl_xor(gm, 1, 8));
    gm = fmaxf(gm, __shfl_xor(gm, 2, 8));
    gm = fmaxf(gm, __shfl_xor(gm, 4, 8));

    float l = 0.f;
#pragma unroll
    for (int i = 0; i < 8; ++i) {
      if (8 * i >= deg) break;
      s[i] = __expf(s[i] - gm);
      l += s[i];
    }
    l += __shfl_xor(l, 1, 8);
    l += __shfl_xor(l, 2, 8);
    l += __shfl_xor(l, 4, 8);

    float a0 = 0.f, a1 = 0.f, a2 = 0.f, a3 = 0.f;
#pragma unroll
    for (int i = 0; i < 8; ++i) {
      if (8 * i >= deg) break;
#pragma unroll
      for (int lj = 0; lj < 8; ++lj) {
        if (8 * i + lj >= deg) break;
        float pj = __shfl(s[i], lj, 8);
        int cj = __shfl(c[i], lj, 8);
        ushort4 vv = *reinterpret_cast<const ushort4*>(Vb + cj * 256 + h * 32 + gl * 4);
        a0 += pj * bf2f(vv.x);
        a1 += pj * bf2f(vv.y);
        a2 += pj * bf2f(vv.z);
        a3 += pj * bf2f(vv.w);
      }
    }
    float rl = 1.f / l;
    ushort4 pkt;
    pkt.x = f2bf(a0 * rl); pkt.y = f2bf(a1 * rl);
    pkt.z = f2bf(a2 * rl); pkt.w = f2bf(a3 * rl);
    *reinterpret_cast<ushort4*>(&att_lds[ni][h * 32 + gl * 4]) = pkt;
  }
  __syncthreads();

  // ---------- out-GEMM (16 waves x 16 cols, direct-f32 Wo) ----------
  {
    int lane = tid & 63, w = tid >> 6;
    int arow = lane & 15, kgrp = lane >> 4;

    short8 a[8];
#pragma unroll
    for (int kk = 0; kk < 8; ++kk)
      a[kk] = *reinterpret_cast<const short8*>(&att_lds[arow][kgrp * 8 + kk * 32]);

    int col = w * 16 + arow;
    f32x4 acc = {0.f, 0.f, 0.f, 0.f};
#pragma unroll
    for (int kk = 0; kk < 8; ++kk) {
      short8 b = wfrag(Wo, kk * 32 + kgrp * 8, col);
      acc = __builtin_amdgcn_mfma_f32_16x16x32_bf16(a[kk], b, acc, 0, 0, 0);
    }
    float bof = bo[col];
#pragma unroll
    for (int r = 0; r < 4; ++r) {
      int row = kgrp * 4 + r;
      float xv = x[(Mbase + row) * 256 + col];
      ylds[row][col] = acc[r] + bof + xv;
    }
  }
  __syncthreads();

  // ---------- LayerNorm (16 rows x 64 segs of 4) ----------
  int r = tid >> 6, seg = tid & 63;
  float sm = 0.f, sq = 0.f;
#pragma unroll
  for (int j = 0; j < 4; ++j) {
    float v = ylds[r][seg * 4 + j];
    sm += v;
    sq += v * v;
  }
  ps[r][seg] = sm;
  pq[r][seg] = sq;
  __syncthreads();
  if (tid < 16) {
    float S = 0.f, Q2 = 0.f;
#pragma unroll
    for (int cc = 0; cc < 64; ++cc) { S += ps[tid][cc]; Q2 += pq[tid][cc]; }
    float mu = S * (1.f / 256.f);
    float var = Q2 * (1.f / 256.f) - mu * mu;
    mu_s[tid] = mu;
    ri_s[tid] = rsqrtf(var + LN_EPS);
  }
  __syncthreads();
  float mu = mu_s[r], ri = ri_s[r];
  float* orow = out + (Mbase + r) * 256;
#pragma unroll
  for (int j = 0; j < 4; ++j) {
    int cc = seg * 4 + j;
    float v = (ylds[r][cc] - mu) * ri * gamma[cc] + beta[cc];
    orow[cc] = v;
  }
}

// ---------------------------------------------------------------------------
extern "C" void kernel_launch(void* const* d_in, const int* in_sizes, int n_in,
                              void* d_out, int out_size, void* d_ws, size_t ws_size,
                              hipStream_t stream) {
  const float* x     = (const float*)d_in[0];
  const int*   edges = (const int*)d_in[1];
  const float* Wq    = (const float*)d_in[2];
  const float* bq    = (const float*)d_in[3];
  const float* Wk    = (const float*)d_in[4];
  const float* bk    = (const float*)d_in[5];
  const float* Wv    = (const float*)d_in[6];
  const float* bv    = (const float*)d_in[7];
  const float* Wo    = (const float*)d_in[8];
  const float* bo    = (const float*)d_in[9];
  const float* gamma = (const float*)d_in[10];
  const float* beta  = (const float*)d_in[11];
  float* out = (float*)d_out;
  int NE = in_sizes[1] / 2;

  // workspace carve (256B aligned)
  char* p = (char*)d_ws;
  auto carve = [&](size_t sz) { char* r = p; p += ((sz + 255) / 256) * 256; return r; };
  unsigned short* Qb   = (unsigned short*)carve((size_t)N_NODES * DMODEL * sizeof(unsigned short));
  unsigned short* Kb   = (unsigned short*)carve((size_t)N_NODES * DMODEL * sizeof(unsigned short));
  unsigned short* Vb   = (unsigned short*)carve((size_t)N_NODES * DMODEL * sizeof(unsigned short));
  int*            cnt  = (int*)carve(N_NODES * sizeof(int));
  int*            colidx = (int*)carve((size_t)N_NODES * MAXDEG * sizeof(int));

  qkv_csr<<<256, 1024, 0, stream>>>(x, Wq, bq, Wk, bk, Wv, bv,
                                    edges, edges + NE, NE, cnt, colidx,
                                    Qb, Kb, Vb);
  attn_out_ln<<<256, 1024, 0, stream>>>(Qb, Kb, Vb, cnt, colidx, Wo,
                                        bo, x, gamma, beta, out);
}